// Round 1
// baseline (439.394 us; speedup 1.0000x reference)
//
#include <hip/hip_runtime.h>
#include <hip/hip_bf16.h>

typedef int v4i __attribute__((ext_vector_type(4)));

static constexpr int MDIM = 8192;
static constexpr int NDIM = 4096;
static constexpr int KDIM = 4096;
static constexpr int BM = 128;
static constexpr int BN = 128;
static constexpr int BK = 64;

// ---------------- quantize x: fp32 -> int8 (16 elems/thread) ----------------
__global__ __launch_bounds__(256) void quant_x_kernel(
    const float* __restrict__ x, const float* __restrict__ in_scale,
    const int* __restrict__ in_zp, int4* __restrict__ xq)
{
    const int idx = blockIdx.x * 256 + threadIdx.x;
    const float s = in_scale[0];
    const int zp = in_zp[0];
    const float zpf = (float)zp;
    const float4* xp = (const float4*)x + (size_t)idx * 4;
    int pk[4];
#pragma unroll
    for (int v = 0; v < 4; ++v) {
        float4 f = xp[v];
        float e[4] = {f.x, f.y, f.z, f.w};
        int p = 0;
#pragma unroll
        for (int j = 0; j < 4; ++j) {
            float q = fminf(fmaxf(rintf(e[j] / s) + zpf, -128.0f), 127.0f);
            p |= (((int)q - zp) & 0xFF) << (8 * j);
        }
        pk[v] = p;
    }
    xq[idx] = make_int4(pk[0], pk[1], pk[2], pk[3]);
}

// ---------------- pack weight: int32 -> int8 (16 elems/thread) ----------------
__global__ __launch_bounds__(256) void pack_w_kernel(
    const int* __restrict__ w, const int* __restrict__ wzp, int4* __restrict__ wq)
{
    const int idx = blockIdx.x * 256 + threadIdx.x;
    const int n = idx >> 8;          // (idx*16)/KDIM, KDIM=4096
    const int zp = wzp[n];
    const int4* wp = (const int4*)w + (size_t)idx * 4;
    int pk[4];
#pragma unroll
    for (int v = 0; v < 4; ++v) {
        int4 ww = wp[v];
        int e[4] = {ww.x, ww.y, ww.z, ww.w};
        int p = 0;
#pragma unroll
        for (int j = 0; j < 4; ++j)
            p |= ((e[j] - zp) & 0xFF) << (8 * j);
        pk[v] = p;
    }
    wq[idx] = make_int4(pk[0], pk[1], pk[2], pk[3]);
}

// ---------------- int8 GEMM: out[m][n] = sum_k xq[m][k]*wq[n][k], dequant epilogue ----------------
// m97-style structure: 128x128 tile, BK=64, 4 waves (2x2), 4x4 16x16x64 frags/wave.
// LDS tiles [128][64B] linear; bank-conflict fix via source-side XOR swizzle
// (chunk ^= (row>>1)&3) applied identically on global src and LDS read (rule #21).
__global__ __launch_bounds__(256) void gemm_i8_kernel(
    const char* __restrict__ Aq, const char* __restrict__ Bq,
    const float* __restrict__ wscale, const float* __restrict__ in_scale,
    const int* __restrict__ bias_int, const float* __restrict__ bias_scale,
    float* __restrict__ out)
{
    __shared__ char As[BM * BK];   // 8 KiB
    __shared__ char Bs[BN * BK];   // 8 KiB

    const int t = threadIdx.x;
    const int lane = t & 63;
    const int wv = t >> 6;
    const int wr = wv >> 1;
    const int wc = wv & 1;

    const int bn = blockIdx.x;   // NDIM/BN = 32
    const int bm = blockIdx.y;   // MDIM/BM = 64

    // staging: 2 global_load_lds_dwordx4 per tile; lin = j*256 + t covers 512x16B
    const int lin0 = t;
    const int lin1 = 256 + t;
    const int row0 = lin0 >> 2;
    const int row1 = lin1 >> 2;
    const int c0 = (lin0 & 3) ^ ((row0 >> 1) & 3);
    const int c1 = (lin1 & 3) ^ ((row1 >> 1) & 3);

    const char* gA0 = Aq + (size_t)(bm * BM + row0) * KDIM + c0 * 16;
    const char* gA1 = Aq + (size_t)(bm * BM + row1) * KDIM + c1 * 16;
    const char* gB0 = Bq + (size_t)(bn * BN + row0) * KDIM + c0 * 16;
    const char* gB1 = Bq + (size_t)(bn * BN + row1) * KDIM + c1 * 16;

    v4i acc[4][4];
#pragma unroll
    for (int m = 0; m < 4; ++m)
#pragma unroll
        for (int n = 0; n < 4; ++n)
            acc[m][n] = (v4i){0, 0, 0, 0};

    const int k0 = lane >> 4;     // 0..3: which 16-byte k-chunk
    const int rlo = lane & 15;    // row/col within fragment

    // LDS read offsets (same swizzle as staging)
    int aOff[4], bOff[4];
#pragma unroll
    for (int m = 0; m < 4; ++m) {
        int row = wr * 64 + m * 16 + rlo;
        int c = k0 ^ ((row >> 1) & 3);
        aOff[m] = row * BK + c * 16;
        int rowb = wc * 64 + m * 16 + rlo;
        int cb = k0 ^ ((rowb >> 1) & 3);
        bOff[m] = rowb * BK + cb * 16;
    }

    for (int kt = 0; kt < KDIM / BK; ++kt) {
        __syncthreads();
        __builtin_amdgcn_global_load_lds(
            (const __attribute__((address_space(1))) void*)gA0,
            (__attribute__((address_space(3))) void*)(As + lin0 * 16), 16, 0, 0);
        __builtin_amdgcn_global_load_lds(
            (const __attribute__((address_space(1))) void*)gA1,
            (__attribute__((address_space(3))) void*)(As + lin1 * 16), 16, 0, 0);
        __builtin_amdgcn_global_load_lds(
            (const __attribute__((address_space(1))) void*)gB0,
            (__attribute__((address_space(3))) void*)(Bs + lin0 * 16), 16, 0, 0);
        __builtin_amdgcn_global_load_lds(
            (const __attribute__((address_space(1))) void*)gB1,
            (__attribute__((address_space(3))) void*)(Bs + lin1 * 16), 16, 0, 0);
        gA0 += BK; gA1 += BK; gB0 += BK; gB1 += BK;
        __syncthreads();   // compiler emits vmcnt(0) drain before this barrier

        v4i a[4], b[4];
#pragma unroll
        for (int m = 0; m < 4; ++m) a[m] = *(const v4i*)(As + aOff[m]);
#pragma unroll
        for (int n = 0; n < 4; ++n) b[n] = *(const v4i*)(Bs + bOff[n]);
#pragma unroll
        for (int m = 0; m < 4; ++m)
#pragma unroll
            for (int n = 0; n < 4; ++n)
                acc[m][n] = __builtin_amdgcn_mfma_i32_16x16x64_i8(a[m], b[n], acc[m][n], 0, 0, 0);
    }

    // epilogue: dequant + bias; C/D layout: col=lane&15, row=(lane>>4)*4+reg
    const float a_s = in_scale[0];
    const int colbase = bn * BN + wc * 64 + rlo;
    const int rowbase = bm * BM + wr * 64 + k0 * 4;
#pragma unroll
    for (int n = 0; n < 4; ++n) {
        const int col = colbase + n * 16;
        const float sc = a_s * wscale[col];
        const float bi = (float)bias_int[col] * bias_scale[col];
#pragma unroll
        for (int m = 0; m < 4; ++m) {
            const int row = rowbase + m * 16;
#pragma unroll
            for (int r = 0; r < 4; ++r) {
                out[(size_t)(row + r) * NDIM + col] = (float)acc[m][n][r] * sc + bi;
            }
        }
    }
}

extern "C" void kernel_launch(void* const* d_in, const int* in_sizes, int n_in,
                              void* d_out, int out_size, void* d_ws, size_t ws_size,
                              hipStream_t stream) {
    const float* x          = (const float*)d_in[0];
    const int*   w_int      = (const int*)d_in[1];
    const float* w_scale    = (const float*)d_in[2];
    const int*   w_zp       = (const int*)d_in[3];
    const float* in_scale   = (const float*)d_in[4];
    const int*   in_zp      = (const int*)d_in[5];
    const int*   bias_int   = (const int*)d_in[6];
    const float* bias_scale = (const float*)d_in[7];
    float* out = (float*)d_out;

    // workspace: xq (M*K int8 = 32 MiB) then wq (N*K int8 = 16 MiB)
    char* xq = (char*)d_ws;
    char* wq = xq + (size_t)MDIM * KDIM;

    quant_x_kernel<<<MDIM * KDIM / 16 / 256, 256, 0, stream>>>(
        x, in_scale, in_zp, (int4*)xq);
    pack_w_kernel<<<NDIM * KDIM / 16 / 256, 256, 0, stream>>>(
        w_int, w_zp, (int4*)wq);

    dim3 grid(NDIM / BN, MDIM / BM);
    gemm_i8_kernel<<<grid, 256, 0, stream>>>(
        xq, wq, w_scale, in_scale, bias_int, bias_scale, out);
}

// Round 3
// 413.176 us; speedup vs baseline: 1.0635x; 1.0635x over previous
//
#include <hip/hip_runtime.h>
#include <hip/hip_bf16.h>

typedef int v4i __attribute__((ext_vector_type(4)));

static constexpr int MDIM = 8192;
static constexpr int NDIM = 4096;
static constexpr int KDIM = 4096;
static constexpr int BM = 256;
static constexpr int BN = 256;
static constexpr int BK = 128;          // i8 elements = bytes per row per K-tile
static constexpr int NT = KDIM / BK;    // 32

// ---------------- quantize x: fp32 -> int8 (16 elems/thread) ----------------
__global__ __launch_bounds__(256) void quant_x_kernel(
    const float* __restrict__ x, const float* __restrict__ in_scale,
    const int* __restrict__ in_zp, int4* __restrict__ xq)
{
    const int idx = blockIdx.x * 256 + threadIdx.x;
    const float s = in_scale[0];
    const float rs = 1.0f / s;          // one divide per thread, not 16
    const int zp = in_zp[0];
    const float zpf = (float)zp;
    const float4* xp = (const float4*)x + (size_t)idx * 4;
    int pk[4];
#pragma unroll
    for (int v = 0; v < 4; ++v) {
        float4 f = xp[v];
        float e[4] = {f.x, f.y, f.z, f.w};
        int p = 0;
#pragma unroll
        for (int j = 0; j < 4; ++j) {
            float q = fminf(fmaxf(rintf(e[j] * rs) + zpf, -128.0f), 127.0f);
            p |= (((int)q - zp) & 0xFF) << (8 * j);
        }
        pk[v] = p;
    }
    xq[idx] = make_int4(pk[0], pk[1], pk[2], pk[3]);
}

// ---------------- pack weight: int32 -> int8 (16 elems/thread) ----------------
__global__ __launch_bounds__(256) void pack_w_kernel(
    const int* __restrict__ w, const int* __restrict__ wzp, int4* __restrict__ wq)
{
    const int idx = blockIdx.x * 256 + threadIdx.x;
    const int n = idx >> 8;          // (idx*16)/KDIM
    const int zp = wzp[n];
    const int4* wp = (const int4*)w + (size_t)idx * 4;
    int pk[4];
#pragma unroll
    for (int v = 0; v < 4; ++v) {
        int4 ww = wp[v];
        int e[4] = {ww.x, ww.y, ww.z, ww.w};
        int p = 0;
#pragma unroll
        for (int j = 0; j < 4; ++j)
            p |= ((e[j] - zp) & 0xFF) << (8 * j);
        pk[v] = p;
    }
    wq[idx] = make_int4(pk[0], pk[1], pk[2], pk[3]);
}

// ---------------- int8 GEMM, 256x256 tile, BK=128, 8 waves, dbuf + counted vmcnt ----------------
// LDS linear (global_load_lds constraint); bank-conflict fix via identical XOR
// permutation on global SOURCE chunk and LDS READ chunk: c ^= (row & 7)  (rule #21).
__global__ __launch_bounds__(512, 2) void gemm_i8_kernel(
    const char* __restrict__ Aq, const char* __restrict__ Bq,
    const float* __restrict__ wscale, const float* __restrict__ in_scale,
    const int* __restrict__ bias_int, const float* __restrict__ bias_scale,
    float* __restrict__ out)
{
    __shared__ char As[2][BM * BK];   // 2 x 32 KiB
    __shared__ char Bs[2][BN * BK];   // 2 x 32 KiB   (total 128 KiB)

    const int t = threadIdx.x;
    const int lane = t & 63;
    const int wv = t >> 6;            // 0..7
    const int wr = wv >> 2;           // 0..1  (wave row: 128 out rows each)
    const int wc = wv & 3;            // 0..3  (wave col: 64 out cols each)

    const int bn = blockIdx.x;        // NDIM/BN = 16
    const int bm = blockIdx.y;        // MDIM/BM = 32

    // ---- staging offsets: 4 A-insts + 4 B-insts per thread per K-tile ----
    // slot j*512+t covers 2048 x 16B = 32KB (256 rows x 8 chunks)
    size_t offA[4], offB[4];
    int dstOff[4];
#pragma unroll
    for (int j = 0; j < 4; ++j) {
        const int slot = j * 512 + t;
        const int row = slot >> 3;
        const int cg = (slot & 7) ^ (row & 7);      // inverse swizzle on source
        offA[j] = (size_t)(bm * BM + row) * KDIM + cg * 16;
        offB[j] = (size_t)(bn * BN + row) * KDIM + cg * 16;
        dstOff[j] = slot * 16;                      // linear LDS dest
    }

    // ---- LDS read offsets (kk=0; kk=1 is ^64 since chunk^4 ≡ +bit6) ----
    const int k0 = lane >> 4;        // 0..3: 16B k-chunk within 64 k-elems
    const int rlo = lane & 15;
    int aOff[8], bOff[4];
#pragma unroll
    for (int m = 0; m < 8; ++m) {
        const int row = wr * 128 + m * 16 + rlo;
        aOff[m] = row * BK + (k0 ^ (row & 7)) * 16;
    }
#pragma unroll
    for (int n = 0; n < 4; ++n) {
        const int row = wc * 64 + n * 16 + rlo;
        bOff[n] = row * BK + (k0 ^ (row & 7)) * 16;
    }

    v4i acc[8][4];
#pragma unroll
    for (int m = 0; m < 8; ++m)
#pragma unroll
        for (int n = 0; n < 4; ++n)
            acc[m][n] = (v4i){0, 0, 0, 0};

#define STAGE(buf, kt)                                                          \
    do {                                                                        \
        _Pragma("unroll")                                                       \
        for (int j = 0; j < 4; ++j)                                             \
            __builtin_amdgcn_global_load_lds(                                   \
                (const __attribute__((address_space(1))) void*)(Aq + offA[j] + (size_t)(kt) * BK), \
                (__attribute__((address_space(3))) void*)(As[buf] + dstOff[j]), \
                16, 0, 0);                                                      \
        _Pragma("unroll")                                                       \
        for (int j = 0; j < 4; ++j)                                             \
            __builtin_amdgcn_global_load_lds(                                   \
                (const __attribute__((address_space(1))) void*)(Bq + offB[j] + (size_t)(kt) * BK), \
                (__attribute__((address_space(3))) void*)(Bs[buf] + dstOff[j]), \
                16, 0, 0);                                                      \
    } while (0)

#define COMPUTE(buf)                                                            \
    do {                                                                        \
        _Pragma("unroll")                                                       \
        for (int kk = 0; kk < 2; ++kk) {                                        \
            v4i a[8], b[4];                                                     \
            _Pragma("unroll")                                                   \
            for (int n = 0; n < 4; ++n)                                         \
                b[n] = *(const v4i*)(Bs[buf] + (bOff[n] ^ (kk << 6)));          \
            _Pragma("unroll")                                                   \
            for (int m = 0; m < 8; ++m)                                         \
                a[m] = *(const v4i*)(As[buf] + (aOff[m] ^ (kk << 6)));          \
            __builtin_amdgcn_s_setprio(1);                                      \
            _Pragma("unroll")                                                   \
            for (int m = 0; m < 8; ++m)                                         \
                _Pragma("unroll")                                               \
                for (int n = 0; n < 4; ++n)                                     \
                    acc[m][n] = __builtin_amdgcn_mfma_i32_16x16x64_i8(          \
                        a[m], b[n], acc[m][n], 0, 0, 0);                        \
            __builtin_amdgcn_s_setprio(0);                                      \
        }                                                                       \
    } while (0)

    // ---- prologue: two tiles in flight ----
    STAGE(0, 0);
    STAGE(1, 1);

    int cur = 0;
#pragma unroll 1
    for (int kt = 0; kt < NT; ++kt) {
        if (kt < NT - 1) {
            asm volatile("s_waitcnt vmcnt(8)" ::: "memory");   // buf[cur] landed; next tile's 8 stay in flight
        } else {
            asm volatile("s_waitcnt vmcnt(0)" ::: "memory");
        }
        __builtin_amdgcn_s_barrier();
        __builtin_amdgcn_sched_barrier(0);
        COMPUTE(cur);
        __builtin_amdgcn_sched_barrier(0);
        __builtin_amdgcn_s_barrier();          // all waves done reading buf[cur]
        if (kt + 2 < NT)
            STAGE(cur, kt + 2);                // safe to overwrite buf[cur]
        cur ^= 1;
    }

    // ---- epilogue: dequant + bias; C/D layout col=lane&15, row=(lane>>4)*4+reg ----
    const float a_s = in_scale[0];
    const int colbase = bn * BN + wc * 64 + rlo;
    const int rowbase = bm * BM + wr * 128 + k0 * 4;
#pragma unroll
    for (int n = 0; n < 4; ++n) {
        const int col = colbase + n * 16;
        const float sc = a_s * wscale[col];
        const float bi = (float)bias_int[col] * bias_scale[col];
#pragma unroll
        for (int m = 0; m < 8; ++m) {
            const int row = rowbase + m * 16;
#pragma unroll
            for (int r = 0; r < 4; ++r) {
                out[(size_t)(row + r) * NDIM + col] = (float)acc[m][n][r] * sc + bi;
            }
        }
    }
#undef STAGE
#undef COMPUTE
}

extern "C" void kernel_launch(void* const* d_in, const int* in_sizes, int n_in,
                              void* d_out, int out_size, void* d_ws, size_t ws_size,
                              hipStream_t stream) {
    const float* x          = (const float*)d_in[0];
    const int*   w_int      = (const int*)d_in[1];
    const float* w_scale    = (const float*)d_in[2];
    const int*   w_zp       = (const int*)d_in[3];
    const float* in_scale   = (const float*)d_in[4];
    const int*   in_zp      = (const int*)d_in[5];
    const int*   bias_int   = (const int*)d_in[6];
    const float* bias_scale = (const float*)d_in[7];
    float* out = (float*)d_out;

    // workspace: xq (M*K int8 = 32 MiB) then wq (N*K int8 = 16 MiB)
    char* xq = (char*)d_ws;
    char* wq = xq + (size_t)MDIM * KDIM;

    quant_x_kernel<<<MDIM * KDIM / 16 / 256, 256, 0, stream>>>(
        x, in_scale, in_zp, (int4*)xq);
    pack_w_kernel<<<NDIM * KDIM / 16 / 256, 256, 0, stream>>>(
        w_int, w_zp, (int4*)wq);

    dim3 grid(NDIM / BN, MDIM / BM);
    gemm_i8_kernel<<<grid, 512, 0, stream>>>(
        xq, wq, w_scale, in_scale, bias_int, bias_scale, out);
}